// Round 10
// baseline (42.376 us; speedup 1.0000x reference)
//
#include <hip/hip_runtime.h>
#include <math.h>

#define TT   16384
#define ADIM 1024
#define NCH  2048    // blocks in fused main kernel (8 rows each)
#define RPB  8       // rows per block
#define NCH2 128     // second-level context chunks (fold 16 each)

typedef unsigned int u32;

// fast tanh: 1 - 2/(e^{2x}+1); saturates correctly for large |x|
__device__ __forceinline__ float ftanh(float x) {
    float e2 = __expf(2.0f * x);
    return 1.0f - 2.0f * __builtin_amdgcn_rcpf(e2 + 1.0f);
}

__device__ __forceinline__ float pdot(float4 p, float4 d, float4 g) {
    return ftanh(p.x + d.x) * g.x + ftanh(p.y + d.y) * g.y +
           ftanh(p.z + d.z) * g.z + ftanh(p.w + d.w) * g.w;
}

// K1: dec GEMV partials. grid=256, block b handles rows [4b, 4b+4)
__global__ void k1_gemv_part(const float* __restrict__ z, const float* __restrict__ W,
                             float* __restrict__ part) {
    int b = blockIdx.x, tid = threadIdx.x;
    float4 acc = {0.f, 0.f, 0.f, 0.f};
#pragma unroll
    for (int i = 0; i < 4; ++i) {
        int d = b * 4 + i;
        float zv = z[d];
        float4 w4 = reinterpret_cast<const float4*>(W)[(size_t)d * 256 + tid];
        acc.x += zv * w4.x; acc.y += zv * w4.y; acc.z += zv * w4.z; acc.w += zv * w4.w;
    }
    reinterpret_cast<float4*>(part)[(size_t)b * 256 + tid] = acc;
}

// K2: reduce 256 partials -> dp[1024]. grid=64, block b covers cols [16b,16b+16)
__global__ void k2_gemv_red(const float* __restrict__ part, const float* __restrict__ bdec,
                            float* __restrict__ dp) {
    int b = blockIdx.x, tid = threadIdx.x;
    int lane = tid & 63, wv = tid >> 6;
    int rsub = lane >> 2;
    int colg = lane & 3;
    float4 acc = {0.f, 0.f, 0.f, 0.f};
#pragma unroll
    for (int i = 0; i < 4; ++i) {
        int row = i * 64 + wv * 16 + rsub;
        float4 v = reinterpret_cast<const float4*>(part)[(size_t)row * 256 + b * 4 + colg];
        acc.x += v.x; acc.y += v.y; acc.z += v.z; acc.w += v.w;
    }
#pragma unroll
    for (int off = 4; off <= 32; off <<= 1) {
        acc.x += __shfl_xor(acc.x, off, 64);
        acc.y += __shfl_xor(acc.y, off, 64);
        acc.z += __shfl_xor(acc.z, off, 64);
        acc.w += __shfl_xor(acc.w, off, 64);
    }
    __shared__ float4 lds[4][4];
    if (lane < 4) lds[wv][lane] = acc;
    __syncthreads();
    if (tid < 4) {
        float4 t = {0.f, 0.f, 0.f, 0.f};
#pragma unroll
        for (int w = 0; w < 4; ++w) {
            float4 v = lds[w][tid];
            t.x += v.x; t.y += v.y; t.z += v.z; t.w += v.w;
        }
        float4 bd = reinterpret_cast<const float4*>(bdec)[b * 4 + tid];
        t.x += bd.x; t.y += bd.y; t.z += bd.z; t.w += bd.w;
        reinterpret_cast<float4*>(dp)[b * 4 + tid] = t;
    }
}

// async global->LDS: each lane of the wave moves 16B; LDS dest is wave-uniform
// base (HW adds lane*16); global src is per-lane (base + lane*16B).
#define STAGE(GSEG, LDSPTR) \
    __builtin_amdgcn_global_load_lds( \
        (const __attribute__((address_space(1))) u32*)(const void*)(GSEG) + (lane << 2), \
        (__attribute__((address_space(3))) u32*)(void*)(LDSPTR), 16, 0, 0)

// K3: fused e-score + softmax context partials; column-sliced waves.
// grid=NCH x 256. Block b rows [8b, 8b+8). Wave wv owns feature cols
// [256*wv, 256*wv+256) for ALL 8 rows. Both streams staged via 16
// back-to-back async global_load_lds per wave (16KB in flight/wave,
// 64KB/block, 2 blocks/CU = 128KB in flight/CU) -> compiler cannot sink.
__global__ void __launch_bounds__(256) k3_fused(
    const float* __restrict__ pre, const float* __restrict__ enc,
    const float* __restrict__ dp, const float* __restrict__ wg,
    const float* __restrict__ bgp, const float* __restrict__ mask,
    float* __restrict__ e_out, float* __restrict__ m_out,
    float* __restrict__ s_out, float* __restrict__ cpart) {
    __shared__ float lbuf[16384];   // 64KB: per-wave 4096 floats (pre 2048 | enc 2048)
    __shared__ float sd[4][RPB];
    int b = blockIdx.x, tid = threadIdx.x;
    int lane = tid & 63, wv = tid >> 6;
    int t0 = b * RPB;
    const float* preb = pre + (size_t)t0 * ADIM + wv * 256;
    const float* encb = enc + (size_t)t0 * ADIM + wv * 256;
    float* wl = lbuf + wv * 4096;

    // issue all 16 row-loads asynchronously (no VGPR cost, not sinkable)
#pragma unroll
    for (int r = 0; r < RPB; ++r) STAGE(preb + (size_t)r * ADIM, wl + r * 256);
#pragma unroll
    for (int r = 0; r < RPB; ++r) STAGE(encb + (size_t)r * ADIM, wl + 2048 + r * 256);

    float4 d4 = reinterpret_cast<const float4*>(dp)[wv * 64 + lane];
    float4 g4 = reinterpret_cast<const float4*>(wg)[wv * 64 + lane];
    float bgv = bgp[0];

    asm volatile("s_waitcnt vmcnt(0)" ::: "memory");

    // Phase A: partial dots over this wave's 256-feature slice (from LDS)
    float dt[RPB];
#pragma unroll
    for (int r = 0; r < RPB; ++r) {
        float4 pv = *reinterpret_cast<const float4*>(&wl[r * 256 + lane * 4]);
        dt[r] = pdot(pv, d4, g4);
    }
#pragma unroll
    for (int r = 0; r < RPB; ++r) {
#pragma unroll
        for (int off = 32; off; off >>= 1) dt[r] += __shfl_xor(dt[r], off, 64);
    }
    if (lane == 0) {
#pragma unroll
        for (int r = 0; r < RPB; ++r) sd[wv][r] = dt[r];
    }
    __syncthreads();
    float et[RPB];
#pragma unroll
    for (int r = 0; r < RPB; ++r)
        et[r] = 2.0f * (sd[0][r] + sd[1][r] + sd[2][r] + sd[3][r] + bgv + mask[t0 + r]);
    if (tid == 0) {
#pragma unroll
        for (int r = 0; r < RPB; ++r) e_out[t0 + r] = et[r];
    }

    // Phase B: block-local softmax pieces (computed redundantly in all threads)
    float m = et[0];
#pragma unroll
    for (int r = 1; r < RPB; ++r) m = fmaxf(m, et[r]);
    float p[RPB], s = 0.f;
#pragma unroll
    for (int r = 0; r < RPB; ++r) { p[r] = __expf(et[r] - m); s += p[r]; }
    if (tid == 0) { m_out[b] = m; s_out[b] = s; }

    // Phase C: weighted accumulation from LDS enc slices
    float4 ca = {0.f, 0.f, 0.f, 0.f};
#pragma unroll
    for (int r = 0; r < RPB; ++r) {
        float4 ev = *reinterpret_cast<const float4*>(&wl[2048 + r * 256 + lane * 4]);
        ca.x += p[r] * ev.x; ca.y += p[r] * ev.y;
        ca.z += p[r] * ev.z; ca.w += p[r] * ev.w;
    }
    // each wave writes its own disjoint column slice
    reinterpret_cast<float4*>(cpart)[(size_t)b * 256 + wv * 64 + lane] = ca;
}

// K4: global M,S + fold NCH chunk partials -> NCH2. grid=NCH2 blocks.
__global__ void __launch_bounds__(256) k4_fold(
    const float* __restrict__ m_arr, const float* __restrict__ s_arr,
    const float* __restrict__ cpart, float* __restrict__ cpart2,
    float* __restrict__ msout) {
    int b = blockIdx.x, tid = threadIdx.x;
    int lane = tid & 63, wv = tid >> 6;
    __shared__ float redm[4], reds[4];
    float mloc = -3.0e38f;
#pragma unroll
    for (int i = 0; i < NCH / 256; ++i) mloc = fmaxf(mloc, m_arr[tid + i * 256]);
#pragma unroll
    for (int off = 32; off; off >>= 1) mloc = fmaxf(mloc, __shfl_xor(mloc, off, 64));
    if (lane == 0) redm[wv] = mloc;
    __syncthreads();
    float M = fmaxf(fmaxf(redm[0], redm[1]), fmaxf(redm[2], redm[3]));
    float4 acc = {0.f, 0.f, 0.f, 0.f};
#pragma unroll
    for (int i = 0; i < NCH / NCH2; ++i) {
        int r = b * (NCH / NCH2) + i;
        float scf = __expf(m_arr[r] - M);
        float4 v = reinterpret_cast<const float4*>(cpart)[(size_t)r * 256 + tid];
        acc.x += scf * v.x; acc.y += scf * v.y; acc.z += scf * v.z; acc.w += scf * v.w;
    }
    reinterpret_cast<float4*>(cpart2)[(size_t)b * 256 + tid] = acc;
    if (b == 0) {
        float sl = 0.f;
#pragma unroll
        for (int i = 0; i < NCH / 256; ++i)
            sl += s_arr[tid + i * 256] * __expf(m_arr[tid + i * 256] - M);
#pragma unroll
        for (int off = 32; off; off >>= 1) sl += __shfl_xor(sl, off, 64);
        if (lane == 0) reds[wv] = sl;
        __syncthreads();
        if (tid == 0) {
            float S = reds[0] + reds[1] + reds[2] + reds[3];
            msout[0] = M;
            msout[1] = 1.0f / S;
        }
    }
}

// K5: final. blocks 0..15: c columns; blocks 16..31: w = exp(e-M)*invS.
__global__ void __launch_bounds__(256) k5_final(
    const float* __restrict__ cpart2, const float* __restrict__ e,
    const float* __restrict__ ms, float* __restrict__ c_out,
    float* __restrict__ w_out) {
    int b = blockIdx.x, tid = threadIdx.x;
    float M = ms[0], invS = ms[1];
    if (b < 16) {
        int rs = tid >> 4;   // 0..15 row-groups
        int cg = tid & 15;   // float4 group within block's 64 cols
        float4 acc = {0.f, 0.f, 0.f, 0.f};
#pragma unroll
        for (int i = 0; i < NCH2 / 16; ++i) {
            int r = rs * (NCH2 / 16) + i;
            float4 v = reinterpret_cast<const float4*>(cpart2)[(size_t)r * 256 + b * 16 + cg];
            acc.x += v.x; acc.y += v.y; acc.z += v.z; acc.w += v.w;
        }
        __shared__ float4 lds[16][16];
        lds[rs][cg] = acc;
        __syncthreads();
        if (tid < 16) {
            float4 t = {0.f, 0.f, 0.f, 0.f};
#pragma unroll
            for (int r = 0; r < 16; ++r) {
                float4 v = lds[r][tid];
                t.x += v.x; t.y += v.y; t.z += v.z; t.w += v.w;
            }
            t.x *= invS; t.y *= invS; t.z *= invS; t.w *= invS;
            reinterpret_cast<float4*>(c_out)[b * 16 + tid] = t;
        }
    } else {
        int base = (b - 16) * 256 + tid;
        float4 ev = reinterpret_cast<const float4*>(e)[base];
        float4 w;
        w.x = __expf(ev.x - M) * invS;
        w.y = __expf(ev.y - M) * invS;
        w.z = __expf(ev.z - M) * invS;
        w.w = __expf(ev.w - M) * invS;
        reinterpret_cast<float4*>(w_out)[base] = w;
    }
}

extern "C" void kernel_launch(void* const* d_in, const int* in_sizes, int n_in,
                              void* d_out, int out_size, void* d_ws, size_t ws_size,
                              hipStream_t stream) {
    const float* dec_z = (const float*)d_in[0];
    // d_in[1] = att_prev (unused)
    const float* pre   = (const float*)d_in[2];
    const float* enc   = (const float*)d_in[3];
    const float* mask  = (const float*)d_in[4];
    const float* W_dec = (const float*)d_in[5];
    const float* b_dec = (const float*)d_in[6];
    const float* wg    = (const float*)d_in[7];
    const float* bg    = (const float*)d_in[8];

    float* out   = (float*)d_out;
    float* c_out = out;            // [1024]
    float* w_out = out + ADIM;     // [16384]

    float* ws = (float*)d_ws;
    float* part   = ws;                           // 256*1024
    float* dp     = part + 256 * ADIM;            // 1024
    float* e_sc   = dp + ADIM;                    // 16384
    float* m_arr  = e_sc + TT;                    // NCH
    float* s_arr  = m_arr + NCH;                  // NCH
    float* cpart  = s_arr + NCH;                  // NCH*1024
    float* cpart2 = cpart + (size_t)NCH * ADIM;   // NCH2*1024
    float* ms     = cpart2 + (size_t)NCH2 * ADIM; // 2

    k1_gemv_part<<<256, 256, 0, stream>>>(dec_z, W_dec, part);
    k2_gemv_red<<<64, 256, 0, stream>>>(part, b_dec, dp);
    k3_fused<<<NCH, 256, 0, stream>>>(pre, enc, dp, wg, bg, mask,
                                      e_sc, m_arr, s_arr, cpart);
    k4_fold<<<NCH2, 256, 0, stream>>>(m_arr, s_arr, cpart, cpart2, ms);
    k5_final<<<32, 256, 0, stream>>>(cpart2, e_sc, ms, c_out, w_out);
}